// Round 1
// 799.112 us; speedup vs baseline: 1.0618x; 1.0618x over previous
//
#include <hip/hip_runtime.h>
#include <hip/hip_bf16.h>

// VQ-VAE forward loss on MI355X.
// loss = 2.25 * mean((emb[argmin] - x)^2)
//      = 2.25/(N*D) * [ sum(x^2) + sum_n min_k(||e_k||^2 - 2 x_n.e_k) ]
// GEMM part (x . e_k) in bf16 MFMA 16x16x32; ||x||^2, ||e||^2 exact fp32.
//
// R3: K-chunked double-buffered pipeline.
//  - BK=96 (3 MFMA k-steps) x 5 chunks, 2-deep LDS double buffer (31 KB total).
//  - Per chunk: issue next chunk's global float4 loads EARLY, compute current
//    chunk (ds_read_b128 + MFMA, B-frags register-double-buffered from L2),
//    then convert+ds_write next chunk LATE (T14 split), one barrier per chunk.
//  - 16 waves/block (1024 thr), 32 codes/wave -> acc[2][4] = 32 AGPR, freeing
//    VGPR budget (128 total @ 4 waves/SIMD) for in-flight staging registers.
//  - All ds_read offsets are compile-time immediates off one lane VGPR.

#define NROWS (64 * 4096)   // 262144
#define DDIM  480
#define KCODES 512
#define BM    64            // rows per block
#define BK    96            // k-chunk: 3 MFMA k-steps
#define NCH   5             // 480 / 96
#define LDSP  104           // padded chunk row stride (bf16): 96 + 8
#define NT    1024          // threads per block (16 waves)

typedef __bf16 bf16x8 __attribute__((ext_vector_type(8)));
typedef float  f32x4  __attribute__((ext_vector_type(4)));

__device__ __forceinline__ ushort f2bf(float v) {
    union { float f; unsigned u; } c; c.f = v;
    unsigned u = c.u;
    u += 0x7fffu + ((u >> 16) & 1u);   // round-to-nearest-even
    return (ushort)(u >> 16);
}

// Convert codebook to bf16 in ws, compute ||e_k||^2 (fp32 exact), zero d_out.
__global__ void vq_setup(const float* __restrict__ e, ushort* __restrict__ ebf,
                         float* __restrict__ esq, float* __restrict__ out) {
    const int k = blockIdx.x;   // one code row per block (1 wave)
    const int t = threadIdx.x;
    if (k == 0 && t == 0) out[0] = 0.0f;
    float s = 0.0f;
    for (int d = t; d < DDIM; d += 64) {
        float v = e[k * DDIM + d];
        s += v * v;
        ebf[k * DDIM + d] = f2bf(v);
    }
    #pragma unroll
    for (int m = 32; m >= 1; m >>= 1) s += __shfl_xor(s, m, 64);
    if (t == 0) esq[k] = s;
}

__global__ __launch_bounds__(NT, 4) void vq_main(const float* __restrict__ x,
        const ushort* __restrict__ ebf, const float* __restrict__ esq,
        float* __restrict__ out) {
    __shared__ ushort xs[2][BM * LDSP];   // 2 x 13312 B = 26624 B
    __shared__ float red[16 * BM];        // per-wave per-row mins
    __shared__ float redw[16];

    const int t    = threadIdx.x;
    const int wave = t >> 6;
    const int lane = t & 63;
    const int lrow = lane & 15;   // MFMA row/col lane index
    const int quad = lane >> 4;

    const float* xb = x + (size_t)blockIdx.x * (BM * DDIM);

    // ---- staging map: chunk = 64 rows x 24 float4; f in [0,1536) ----
    // f0 = t (all threads), f1 = 1024 + t (threads 0..511 only; wave-uniform)
    const int f0 = t;
    const int r0 = f0 / 24, c0f = (f0 % 24) * 4;
    const int f1 = NT + t;
    const int r1 = f1 / 24, c1f = (f1 % 24) * 4;
    const bool has1 = (t < 512);

    const float* g0 = xb + r0 * DDIM + c0f;
    const float* g1 = xb + r1 * DDIM + c1f;   // only dereferenced if has1
    const int l0 = r0 * LDSP + c0f;
    const int l1 = r1 * LDSP + c1f;

    float xsq = 0.0f;

    // ---- prologue: stage chunk 0 into xs[0] ----
    {
        float4 v0 = *(const float4*)g0;
        float4 v1;
        if (has1) v1 = *(const float4*)g1;
        xsq += v0.x * v0.x + v0.y * v0.y + v0.z * v0.z + v0.w * v0.w;
        ushort4 b;
        b.x = f2bf(v0.x); b.y = f2bf(v0.y); b.z = f2bf(v0.z); b.w = f2bf(v0.w);
        *(ushort4*)(&xs[0][l0]) = b;
        if (has1) {
            xsq += v1.x * v1.x + v1.y * v1.y + v1.z * v1.z + v1.w * v1.w;
            ushort4 b1;
            b1.x = f2bf(v1.x); b1.y = f2bf(v1.y); b1.z = f2bf(v1.z); b1.w = f2bf(v1.w);
            *(ushort4*)(&xs[0][l1]) = b1;
        }
    }

    // ---- per-wave code slice: 32 codes ----
    const int code0 = wave * 32;
    const ushort* bp0 = ebf + (size_t)(code0 + lrow) * DDIM + quad * 8;
    const ushort* bp1 = bp0 + (size_t)16 * DDIM;

    f32x4 acc[2][4];   // [coltile][rowtile]
    #pragma unroll
    for (int c = 0; c < 2; ++c)
        #pragma unroll
        for (int r = 0; r < 4; ++r) acc[c][r] = (f32x4){0.f, 0.f, 0.f, 0.f};

    bf16x8 Bb[2][2];   // double-buffered B fragments (parity on global dk)
    Bb[0][0] = *(const bf16x8*)bp0;
    Bb[0][1] = *(const bf16x8*)bp1;

    __syncthreads();

    // ---- main pipeline: 5 chunks, compute cur while staging next ----
    #pragma unroll
    for (int t5 = 0; t5 < NCH; ++t5) {
        float4 v0, v1;
        if (t5 < NCH - 1) {   // issue next chunk's loads EARLY
            v0 = *(const float4*)(g0 + (t5 + 1) * BK);
            if (has1) v1 = *(const float4*)(g1 + (t5 + 1) * BK);
        }
        #pragma unroll
        for (int k3 = 0; k3 < 3; ++k3) {
            const int dk = t5 * 3 + k3;
            const int pc = dk & 1;
            if (dk < 14) {   // prefetch B for next k-step (crosses chunk edge)
                Bb[pc ^ 1][0] = *(const bf16x8*)(bp0 + (dk + 1) * 32);
                Bb[pc ^ 1][1] = *(const bf16x8*)(bp1 + (dk + 1) * 32);
            }
            #pragma unroll
            for (int r = 0; r < 4; ++r) {
                bf16x8 A = *(const bf16x8*)(&xs[t5 & 1][(r * 16 + lrow) * LDSP + k3 * 32 + quad * 8]);
                acc[0][r] = __builtin_amdgcn_mfma_f32_16x16x32_bf16(A, Bb[pc][0], acc[0][r], 0, 0, 0);
                acc[1][r] = __builtin_amdgcn_mfma_f32_16x16x32_bf16(A, Bb[pc][1], acc[1][r], 0, 0, 0);
            }
        }
        if (t5 < NCH - 1) {   // convert + ds_write LATE, into the other buffer
            xsq += v0.x * v0.x + v0.y * v0.y + v0.z * v0.z + v0.w * v0.w;
            ushort4 b;
            b.x = f2bf(v0.x); b.y = f2bf(v0.y); b.z = f2bf(v0.z); b.w = f2bf(v0.w);
            *(ushort4*)(&xs[(t5 & 1) ^ 1][l0]) = b;
            if (has1) {
                xsq += v1.x * v1.x + v1.y * v1.y + v1.z * v1.z + v1.w * v1.w;
                ushort4 b1;
                b1.x = f2bf(v1.x); b1.y = f2bf(v1.y); b1.z = f2bf(v1.z); b1.w = f2bf(v1.w);
                *(ushort4*)(&xs[(t5 & 1) ^ 1][l1]) = b1;
            }
        }
        __syncthreads();   // one barrier per chunk
    }

    // ---- fold: min_k (esq[k] - 2*dot); acc[c][r][j] is (row=quad*4+j, col=lrow)
    float rmin[4][4];
    #pragma unroll
    for (int r = 0; r < 4; ++r)
        #pragma unroll
        for (int j = 0; j < 4; ++j) rmin[r][j] = 1e30f;
    #pragma unroll
    for (int c = 0; c < 2; ++c) {
        float es = esq[code0 + c * 16 + lrow];
        #pragma unroll
        for (int r = 0; r < 4; ++r)
            #pragma unroll
            for (int j = 0; j < 4; ++j)
                rmin[r][j] = fminf(rmin[r][j], es - 2.0f * acc[c][r][j]);
    }

    // ---- cross-lane min over the 16 col lanes (bits 0..3, stays in quad) ----
    #pragma unroll
    for (int r = 0; r < 4; ++r)
        #pragma unroll
        for (int j = 0; j < 4; ++j) {
            float v = rmin[r][j];
            v = fminf(v, __shfl_xor(v, 1, 64));
            v = fminf(v, __shfl_xor(v, 2, 64));
            v = fminf(v, __shfl_xor(v, 4, 64));
            v = fminf(v, __shfl_xor(v, 8, 64));
            if (lrow == 0) red[wave * 64 + r * 16 + quad * 4 + j] = v;
        }
    __syncthreads();

    // ---- combine: min across 16 waves per row, + sum(x^2), block reduce ----
    float val = xsq;
    if (t < 64) {
        float m = red[t];
        #pragma unroll
        for (int w = 1; w < 16; ++w) m = fminf(m, red[w * 64 + t]);
        val += m;
    }
    #pragma unroll
    for (int m = 32; m >= 1; m >>= 1) val += __shfl_xor(val, m, 64);
    if (lane == 0) redw[wave] = val;
    __syncthreads();
    if (t == 0) {
        const float SCALE = 2.25f / ((float)NROWS * (float)DDIM);
        float s = 0.f;
        #pragma unroll
        for (int w = 0; w < 16; ++w) s += redw[w];
        atomicAdd(out, s * SCALE);
    }
}

extern "C" void kernel_launch(void* const* d_in, const int* in_sizes, int n_in,
                              void* d_out, int out_size, void* d_ws, size_t ws_size,
                              hipStream_t stream) {
    (void)in_sizes; (void)n_in; (void)out_size; (void)ws_size;
    const float* x = (const float*)d_in[0];   // [262144, 480] fp32
    const float* e = (const float*)d_in[1];   // [512, 480] fp32
    float* out = (float*)d_out;               // scalar fp32
    ushort* ebf = (ushort*)d_ws;                              // 512*480*2 = 491520 B
    float*  esq = (float*)((char*)d_ws + KCODES * DDIM * 2);  // 512*4 B

    vq_setup<<<KCODES, 64, 0, stream>>>(e, ebf, esq, out);
    vq_main<<<NROWS / BM, NT, 0, stream>>>(x, ebf, esq, out);
}